// Round 22
// baseline (390.427 us; speedup 1.0000x reference)
//
#include <hip/hip_runtime.h>
#include <stdint.h>

typedef unsigned short u16;
typedef unsigned int   u32;
typedef _Float16 f16x8 __attribute__((ext_vector_type(8)));
typedef __attribute__((ext_vector_type(16))) float f16v;

#define JJ 17
#define CC 128
#define BB 3
#define ROWS (BB*JJ)     // 51
#define PP 64
#define XP 132           // xh pitch (u16): 264B rows, b64 frags, 2-bank stride (free)
#define HTP 68           // h1t pitch (u16): 136B -> 34dw stride, 2-way bank (free), 8B-aligned
#define NLAYERS 5
#define NT 512

#define XH_OFF   0                        // xh  [64][132] u16 = 16896
#define HT_OFF   16896                    // h1t [128][68] u16 = 17408 -> 34304
#define DIAG_OFF 34304                    // [64] f32 = 256
#define LDS_BYTES (DIAG_OFF + 256)        // 34560 -> 2 blocks/CU (VGPR-capped at 16 waves)

#define MFMA __builtin_amdgcn_mfma_f32_32x32x16_f16

__device__ __forceinline__ u16 h2b(_Float16 h) {
  union { _Float16 h; u16 b; } c; c.h = h; return c.b;
}
__device__ __forceinline__ _Float16 b2h(u16 b) {
  union { u16 b; _Float16 h; } c; c.b = b; return c.h;
}
__device__ __forceinline__ float wred(float v) {
  #pragma unroll
  for (int m = 32; m >= 1; m >>= 1) v += __shfl_xor(v, m, 64);
  return v;
}
__device__ __forceinline__ f16x8 u4f8(uint4 v) {
  union { uint4 u; f16x8 f; } c; c.u = v; return c.f;
}
__device__ __forceinline__ f16x8 mk8(uint2 a, uint2 b) {
  union { uint4 u; f16x8 f; } c;
  c.u.x = a.x; c.u.y = a.y; c.u.z = b.x; c.u.w = b.y;
  return c.f;
}

// ---- setup: W -> f16 wave-coalesced frag layout ws2[w][ks][g][col][8];
//      amix A-frags [t][i][g][nl][8] for the 64-row (BB=3) tile geometry
__global__ void __launch_bounds__(256)
wprep(const float* __restrict__ W0, const float* __restrict__ W1,
      const float* __restrict__ adj, u16* __restrict__ ws2,
      u16* __restrict__ amixf)
{
  __shared__ float wt[64*130];
  const int w01 = blockIdx.x;
  const float* Wp = w01 ? W1 : W0;
  const int tid = threadIdx.x;
  if (w01 == 0) {
    for (int t = tid; t < 2*3*2*256; t += 256) {   // 3072
      int e  = t & 7, nl = (t >> 3) & 31, g = (t >> 8) & 1;
      int i  = (t >> 9) % 3, tt = t / 1536;        // tile 0..1
      const int kslo = tt;                          // 0 or 1
      int row = tt*32 + nl;
      int k   = (kslo + i)*16 + 8*g + e;
      float v = 0.f;
      if (row < ROWS && k < ROWS && (row/JJ) == (k/JJ) && (row%JJ) != (k%JJ))
        v = 0.8f * adj[(row%JJ)*JJ + (k%JJ)];
      amixf[t] = h2b((_Float16)v);
    }
  }
  for (int kh = 0; kh < 2; ++kh) {
    if (kh) __syncthreads();
    #pragma unroll
    for (int i = 0; i < 32; ++i) {
      int idx = tid + i*256;           // [64 kk][128 col] coalesced read
      int kk = idx >> 7, col = idx & 127;
      wt[kk*130 + col] = Wp[(kh*64 + kk)*128 + col];
    }
    __syncthreads();
    #pragma unroll
    for (int i = 0; i < 32; ++i) {
      int idx = tid + i*256;           // 0..8191: e|col|g|ksl bits
      int e = idx & 7, col = (idx >> 3) & 127;
      int g = (idx >> 10) & 1, ksl = idx >> 11;    // 0..3
      int kk = ksl*16 + 8*g + e;                   // local k in this 64-half
      ws2[(size_t)w01*16384 + kh*8192 + idx] = h2b((_Float16)wt[kk*130 + col]);
    }
  }
}

__global__ void __launch_bounds__(NT, 4)
gconv_fused(const float* __restrict__ x, const float* __restrict__ x0,
            const float* __restrict__ adj, const u16* __restrict__ ws2,
            const u16* __restrict__ amixf, const float* __restrict__ bvec,
            const float* __restrict__ gamma, const float* __restrict__ beta,
            float* __restrict__ out, int totRows)
{
  extern __shared__ char smem[];
  u16*   xh    = (u16*)(smem + XH_OFF);    // [64][132] x (f16)
  u16*   h1t   = (u16*)(smem + HT_OFF);    // [128 col][68] f16 H1^T
  float* diag8 = (float*)(smem + DIAG_OFF);// [64]

  const int tid  = threadIdx.x;
  const int lane = tid & 63;
  const int wid  = tid >> 6;        // 0..7
  const int wm   = wid >> 2;        // 0..1  M-tile (32 rows)
  const int wn   = wid & 3;         // 0..3  N-tile (32 cols)
  const int g    = lane >> 5;
  const int nl   = lane & 31;
  const int ccol = wn*32 + nl;
  const int grow0 = blockIdx.x * ROWS;
  const int kslo = wm;              // mix K-window start tile

  // ---- x0 (pre-scaled 0.2) -> 8 packed-f16 regs, accumulator layout
  u32 x0p[8];
  #pragma unroll
  for (int qp = 0; qp < 8; ++qp) {
    u32 pk = 0;
    #pragma unroll
    for (int h = 0; h < 2; ++h) {
      int q = qp*2 + h;
      int row = wm*32 + (q&3) + 8*(q>>2) + 4*g;
      int grow = grow0 + row;
      u16 bits = 0;
      if (row < ROWS && grow < totRows)
        bits = h2b((_Float16)(0.2f * x0[(size_t)grow*CC + ccol]));
      pk |= ((u32)bits) << (16*h);
    }
    x0p[qp] = pk;
  }
  const float bias_c = bvec[ccol];

  // ---- x -> xh f16 plane (float4 in); pad rows zero
  #pragma unroll
  for (int i = 0; i < 4; ++i) {
    int el4 = tid + i*NT;              // 2048 float4 = 64 rows x 128
    int r = el4 >> 5, c4 = (el4 & 31) << 2;
    float4 v = make_float4(0.f, 0.f, 0.f, 0.f);
    if (r < ROWS && (grow0 + r) < totRows)
      v = *(const float4*)&x[(size_t)(grow0 + r)*CC + c4];
    u16 s0 = h2b((_Float16)v.x), s1 = h2b((_Float16)v.y);
    u16 s2 = h2b((_Float16)v.z), s3 = h2b((_Float16)v.w);
    *(uint2*)&xh[r*XP + c4] = make_uint2((u32)s0 | ((u32)s1<<16), (u32)s2 | ((u32)s3<<16));
  }
  if (tid >= 256 && tid < 256 + PP) {
    int t = tid - 256;
    int j = t % JJ;
    diag8[t] = (t < ROWS) ? 0.8f * adj[j*JJ + j] : 0.f;
  }
  __syncthreads();

  const int arow = (wm*32 + nl)*XP;                 // A base (+= ks*16 + 8g)
  const u16* pw0 = ws2 + (size_t)g*1024 + ccol*8;   // W0 frags: + ks*2048
  const u16* pw1 = pw0 + 16384;                     // W1
  const u16* amp = amixf + ((wm*3*2) + g)*256 + nl*8;  // + i*512

  // ================= layer loop (2 barriers) =================
  #pragma unroll 1
  for (int layer = 0; layer < NLAYERS; ++layer) {
    f16v acc0, acc1;
    #pragma unroll
    for (int i = 0; i < 16; ++i) { acc0[i] = 0.f; acc1[i] = 0.f; }

    // ---- GEMM: A from LDS (b64 pairs), W from L2 (coalesced dwordx4, prefetch-1)
    f16x8 b0 = u4f8(*(const uint4*)(pw0));
    f16x8 b1 = u4f8(*(const uint4*)(pw1));
    #pragma unroll
    for (int ks = 0; ks < 8; ++ks) {
      f16x8 nb0 = b0, nb1 = b1;
      if (ks < 7) {
        nb0 = u4f8(*(const uint4*)(pw0 + (ks+1)*2048));
        nb1 = u4f8(*(const uint4*)(pw1 + (ks+1)*2048));
      }
      const int o = arow + ks*16 + 8*g;
      f16x8 ah = mk8(*(const uint2*)&xh[o], *(const uint2*)&xh[o+4]);
      acc0 = MFMA(ah, b0, acc0, 0, 0, 0);
      acc1 = MFMA(ah, b1, acc1, 0, 0, 0);
      __builtin_amdgcn_sched_barrier(0);   // cap liveness at one prefetch depth
      b0 = nb0; b1 = nb1;
    }

    // ---- epilogue: acc1 (X@W1) -> h1t transposed, f16 pairs (8 u32 writes)
    #pragma unroll
    for (int qp = 0; qp < 8; ++qp) {
      int q = qp*2;
      int row = wm*32 + (q&3) + 8*(q>>2) + 4*g;      // even; row+1 is q+1
      u32 pk = (u32)h2b((_Float16)acc1[q]) | ((u32)h2b((_Float16)acc1[q+1]) << 16);
      *(u32*)&h1t[ccol*HTP + row] = pk;
    }
    __syncthreads();   // (1) h1t complete

    // ---- mix GEMM: acc1 (reused) = Amix * H1; 3 MFMAs (block-diag window)
    #pragma unroll
    for (int i = 0; i < 16; ++i) acc1[i] = 0.f;
    #pragma unroll
    for (int i = 0; i < 3; ++i) {
      f16x8 am = u4f8(*(const uint4*)(amp + i*512));
      const int hidx = ccol*HTP + (kslo + i)*16 + 8*g;
      f16x8 hb = mk8(*(const uint2*)&h1t[hidx], *(const uint2*)&h1t[hidx+4]);
      acc1 = MFMA(am, hb, acc1, 0, 0, 0);
    }

    // ---- combine: x' = 0.2x0 + diag*acc0 + mix + b -> xh (f16)
    #pragma unroll
    for (int q = 0; q < 16; ++q) {
      int row = wm*32 + (q&3) + 8*(q>>2) + 4*g;
      float x0v = (float)b2h((u16)(x0p[q>>1] >> (16*(q&1))));
      float v = x0v + diag8[row]*acc0[q] + acc1[q] + bias_c;
      xh[row*XP + ccol] = h2b((_Float16)v);
    }
    __syncthreads();   // (2) xh ready for next layer; h1t reads drained
  }

  // ---- LayerNorm + store (reads f16 xh), 8 waves
  float ga = gamma[lane], g2 = gamma[64+lane];
  float ba = beta[lane],  b2f = beta[64+lane];
  #pragma unroll 1
  for (int i = 0; i < 7; ++i) {
    int r = wid + 8*i;             // wave-uniform, 0..55
    if (r >= ROWS) continue;
    int grow = grow0 + r;
    if (grow >= totRows) continue;
    float xa = (float)b2h(xh[r*XP + lane]);
    float xc = (float)b2h(xh[r*XP + 64 + lane]);
    float mu = wred(xa + xc) * (1.f/128.f);
    float da = xa - mu, dc = xc - mu;
    float vs = wred(da*da + dc*dc) * (1.f/128.f);
    float rs = rsqrtf(vs + 1e-10f);
    size_t ob = (size_t)grow*CC;
    out[ob + lane]      = da*rs*ga + ba;
    out[ob + 64 + lane] = dc*rs*g2 + b2f;
  }
}

extern "C" void kernel_launch(void* const* d_in, const int* in_sizes, int n_in,
                              void* d_out, int out_size, void* d_ws, size_t ws_size,
                              hipStream_t stream) {
  const float* x   = (const float*)d_in[0];
  const float* x0  = (const float*)d_in[1];
  const float* adj = (const float*)d_in[2];
  const float* W0  = (const float*)d_in[3];
  const float* W1  = (const float*)d_in[4];
  const float* bv  = (const float*)d_in[5];
  const float* ga  = (const float*)d_in[6];
  const float* be  = (const float*)d_in[7];
  u16* ws2   = (u16*)d_ws;                      // [2][8][2][128][8] f16 = 65536 B
  u16* amixf = (u16*)((char*)d_ws + 65536);     // [2][3][2][32][8] f16 = 6144 B
  int totRows = in_sizes[0] / CC;
  int nBatch  = totRows / JJ;
  int grid    = (nBatch + BB - 1) / BB;
  wprep<<<dim3(2), dim3(256), 0, stream>>>(W0, W1, adj, ws2, amixf);
  gconv_fused<<<dim3(grid), dim3(NT), LDS_BYTES, stream>>>(
      x, x0, adj, ws2, amixf, bv, ga, be, (float*)d_out, totRows);
}